// Round 1
// baseline (397.086 us; speedup 1.0000x reference)
//
#include <hip/hip_runtime.h>

#define NB 16
#define NVEC 2048
#define NDIM 32
#define NW 4
#define NHID 128
#define NCLASS 10
#define MS 16              // m-splits for k_U (each block reduces 128 m's)
#define USIZE (129 * 32)   // 4128 floats per b: rows 0..127 = fw2@V, row 128 = fb2^T@V

// tanh-approx GELU; validated absmax vs ref in prior session.
__device__ __forceinline__ float gelu_fast(float x) {
    float t = 1.5957691216057308f * x * (1.0f + 0.044715f * x * x);
    return x / (1.0f + __expf(-t));
}

// ---------------------------------------------------------------------------
// Embed gather (float4) + out=bias init + zero U0 for the first k_U's atomics.
// grid 1024 x 256: one float4 of X per thread.
__global__ __launch_bounds__(256) void k_embed(const int* __restrict__ data,
                                               const float* __restrict__ emb,
                                               const float* __restrict__ bf,
                                               float* __restrict__ X,
                                               float* __restrict__ out,
                                               float* __restrict__ U0) {
    int gid = blockIdx.x * 256 + threadIdx.x;      // NB*NVEC*NDIM/4 = 262144
    int row = gid >> 3, sub = gid & 7;             // 8 float4 per 32-float row
    ((float4*)X)[gid] = ((const float4*)emb)[data[row] * 8 + sub];
    if (gid < NB * USIZE) U0[gid] = 0.f;
    if (blockIdx.x == 0 && threadIdx.x < NB * NCLASS)
        out[threadIdx.x] = bf[threadIdx.x % NCLASS];
}

// ---------------------------------------------------------------------------
// U[b] = fw2 @ V[b] (+ bias row), m-split over MS blocks, accumulated with
// hw f32 atomics into the pre-zeroed U buffer. 1024 threads -> 16 waves/CU
// (vs 4 before): per thread 1 k-row x 4 d over 128 m.
__global__ __launch_bounds__(1024) void k_U(const float* __restrict__ V,
                                            const float* __restrict__ fw2,
                                            const float* __restrict__ fb2,
                                            float* __restrict__ U) {
    __shared__ float Vs[128 * 32];       // [mm][d], 16 KB
    __shared__ float fw2s[128][33];      // [k][mm] pad 1 -> conflict-free
    __shared__ float cred[4][33];
    int ms = blockIdx.x, b = blockIdx.y;
    int tid = threadIdx.x;
    int m0 = ms * 128;
    ((float4*)Vs)[tid] = ((const float4*)(V + (b * NVEC + m0) * NDIM))[tid];
    int k1 = tid & 127, d0 = (tid >> 7) * 4;   // d-group uniform per wave -> Vs broadcast
    float acc[4] = {0.f, 0.f, 0.f, 0.f};
    for (int s = 0; s < 4; ++s) {
        __syncthreads();                 // covers Vs (s=0) + fw2s reuse
        int moff = m0 + s * 32;
#pragma unroll
        for (int j = 0; j < 4; ++j) {
            int i = tid + j * 1024;
            fw2s[i >> 5][i & 31] = fw2[(i >> 5) * NVEC + moff + (i & 31)];
        }
        __syncthreads();
#pragma unroll 8
        for (int mm = 0; mm < 32; ++mm) {
            float w = fw2s[k1][mm];
            float4 v = *(const float4*)&Vs[(s * 32 + mm) * 32 + d0];
            acc[0] += w * v.x; acc[1] += w * v.y;
            acc[2] += w * v.z; acc[3] += w * v.w;
        }
    }
    float* Ub = U + b * USIZE;
#pragma unroll
    for (int j = 0; j < 4; ++j)
        unsafeAtomicAdd(&Ub[k1 * 32 + d0 + j], acc[j]);
    // bias row partial: sum_m fb2[m0+m] * Vs[m][d]
    if (tid < 128) {
        int d = tid & 31, seg = tid >> 5;
        float ca = 0.f;
#pragma unroll 8
        for (int mm = seg * 32; mm < seg * 32 + 32; ++mm)
            ca += fb2[m0 + mm] * Vs[mm * 32 + d];
        cred[seg][d] = ca;
    }
    __syncthreads();
    if (tid < 32)
        unsafeAtomicAdd(&Ub[128 * 32 + tid],
                        cred[0][tid] + cred[1][tid] + cred[2][tid] + cred[3][tid]);
}

// ---------------------------------------------------------------------------
// Fused h+apply, single 64-row pass. grid (NVEC/64, NB), 256 threads.
// Loads FINAL U (16.5 KB, no 16x partial re-reduce), zeros the other U buffer
// for the next layer's k_U. LAST: fold the classifier (k_final) in-register.
// LDS ~73.5 KiB -> 2 blocks/CU.
template <bool LAST>
__global__ __launch_bounds__(256) void k_applyF(const float* __restrict__ X,
                                                const float* __restrict__ fw1l,
                                                const float* __restrict__ fb1l,
                                                const float* __restrict__ U,
                                                float* __restrict__ Unext,
                                                float* __restrict__ Vout,
                                                const float* __restrict__ Wf,
                                                float* __restrict__ out) {
    __shared__ float Us[USIZE];          // 4128
    __shared__ float w1s[NDIM * NHID];   // 4096, [d][k]
    __shared__ float xs[64][33];         // padded: conflict-free row reads
    __shared__ float hs[64 * 132];       // [r][k]
    __shared__ float ored[4][NCLASS];
    int ng = blockIdx.x, b = blockIdx.y;
    int tid = threadIdx.x;
    int n0 = ng * 64;

    for (int i4 = tid; i4 < USIZE / 4; i4 += 256)
        ((float4*)Us)[i4] = ((const float4*)(U + (size_t)b * USIZE))[i4];
#pragma unroll
    for (int j = 0; j < 4; ++j)
        ((float4*)w1s)[tid + j * 256] = ((const float4*)fw1l)[tid + j * 256];
#pragma unroll
    for (int j = 0; j < 2; ++j) {
        int i4 = tid + j * 256;
        float4 v = ((const float4*)(X + (b * NVEC + n0) * NDIM))[i4];
        int r = i4 >> 3, c4 = (i4 & 7) * 4;
        xs[r][c4] = v.x; xs[r][c4 + 1] = v.y;
        xs[r][c4 + 2] = v.z; xs[r][c4 + 3] = v.w;
    }
    if constexpr (!LAST) {               // zero next layer's U (512 blocks * 129 = NB*USIZE)
        int bid = b * 32 + ng;
        for (int i = tid; i < 129; i += 256) Unext[bid * 129 + i] = 0.f;
    }
    __syncthreads();

    {   // h = gelu(X@fw1 + fb1): 4 rows x 8 k per thread
        int kg = tid & 15, rg = tid >> 4;
        int k0 = kg * 8, r0 = rg * 4;
        float acc[4][8];
#pragma unroll
        for (int j = 0; j < 8; ++j) {
            float bv = fb1l[k0 + j];
            acc[0][j] = bv; acc[1][j] = bv; acc[2][j] = bv; acc[3][j] = bv;
        }
#pragma unroll 8
        for (int d = 0; d < NDIM; ++d) {
            float4 wa = *(const float4*)&w1s[d * NHID + k0];
            float4 wb = *(const float4*)&w1s[d * NHID + k0 + 4];
            float wk[8] = {wa.x, wa.y, wa.z, wa.w, wb.x, wb.y, wb.z, wb.w};
            float x0 = xs[r0][d], x1 = xs[r0 + 1][d];
            float x2 = xs[r0 + 2][d], x3 = xs[r0 + 3][d];
#pragma unroll
            for (int j = 0; j < 8; ++j) {
                acc[0][j] += x0 * wk[j];
                acc[1][j] += x1 * wk[j];
                acc[2][j] += x2 * wk[j];
                acc[3][j] += x3 * wk[j];
            }
        }
#pragma unroll
        for (int r = 0; r < 4; ++r) {
            float4 o0, o1;
            o0.x = gelu_fast(acc[r][0]); o0.y = gelu_fast(acc[r][1]);
            o0.z = gelu_fast(acc[r][2]); o0.w = gelu_fast(acc[r][3]);
            o1.x = gelu_fast(acc[r][4]); o1.y = gelu_fast(acc[r][5]);
            o1.z = gelu_fast(acc[r][6]); o1.w = gelu_fast(acc[r][7]);
            *(float4*)&hs[(r0 + r) * 132 + k0] = o0;
            *(float4*)&hs[(r0 + r) * 132 + k0 + 4] = o1;
        }
    }
    __syncthreads();

    {   // apply: V_new = h @ U + U[128,:]; 2 rows x 4 d per thread (32 FMA / 6 LDS reads)
        int dg = tid & 7, rga = tid >> 3;
        int d0 = dg * 4, r0 = rga * 2;
        float4 a0 = *(const float4*)&Us[NHID * 32 + d0];
        float4 a1 = a0;
#pragma unroll 8
        for (int k = 0; k < NHID; k += 4) {
            float4 h0 = *(const float4*)&hs[r0 * 132 + k];
            float4 h1 = *(const float4*)&hs[(r0 + 1) * 132 + k];
            float4 u0 = *(const float4*)&Us[(k + 0) * 32 + d0];
            float4 u1 = *(const float4*)&Us[(k + 1) * 32 + d0];
            float4 u2 = *(const float4*)&Us[(k + 2) * 32 + d0];
            float4 u3 = *(const float4*)&Us[(k + 3) * 32 + d0];
            a0.x += h0.x * u0.x + h0.y * u1.x + h0.z * u2.x + h0.w * u3.x;
            a0.y += h0.x * u0.y + h0.y * u1.y + h0.z * u2.y + h0.w * u3.y;
            a0.z += h0.x * u0.z + h0.y * u1.z + h0.z * u2.z + h0.w * u3.z;
            a0.w += h0.x * u0.w + h0.y * u1.w + h0.z * u2.w + h0.w * u3.w;
            a1.x += h1.x * u0.x + h1.y * u1.x + h1.z * u2.x + h1.w * u3.x;
            a1.y += h1.x * u0.y + h1.y * u1.y + h1.z * u2.y + h1.w * u3.y;
            a1.z += h1.x * u0.z + h1.y * u1.z + h1.z * u2.z + h1.w * u3.z;
            a1.w += h1.x * u0.w + h1.y * u1.w + h1.z * u2.w + h1.w * u3.w;
        }
        if constexpr (!LAST) {
            *(float4*)&Vout[(b * NVEC + n0 + r0) * NDIM + d0] = a0;
            *(float4*)&Vout[(b * NVEC + n0 + r0 + 1) * NDIM + d0] = a1;
        } else {
            // classifier fused: out[b,c] += sum V[n,d] * Wf[n*32+d, c]
            float accC[NCLASS];
#pragma unroll
            for (int c = 0; c < NCLASS; ++c) accC[c] = 0.f;
            float va[2][4] = {{a0.x, a0.y, a0.z, a0.w}, {a1.x, a1.y, a1.z, a1.w}};
#pragma unroll
            for (int r = 0; r < 2; ++r)
#pragma unroll
                for (int dd = 0; dd < 4; ++dd) {
                    int jj = (n0 + r0 + r) * NDIM + d0 + dd;
                    const float2* wr = (const float2*)(Wf + (size_t)jj * NCLASS);
                    float v = va[r][dd];
#pragma unroll
                    for (int p = 0; p < 5; ++p) {
                        float2 w = wr[p];
                        accC[2 * p]     += v * w.x;
                        accC[2 * p + 1] += v * w.y;
                    }
                }
            int lane = tid & 63, wv = tid >> 6;
#pragma unroll
            for (int c = 0; c < NCLASS; ++c)
#pragma unroll
                for (int off = 32; off >= 1; off >>= 1)
                    accC[c] += __shfl_down(accC[c], off, 64);
            if (lane == 0) {
#pragma unroll
                for (int c = 0; c < NCLASS; ++c) ored[wv][c] = accC[c];
            }
            __syncthreads();
            if (tid < NCLASS)
                atomicAdd(&out[b * NCLASS + tid],
                          ored[0][tid] + ored[1][tid] + ored[2][tid] + ored[3][tid]);
        }
    }
}

// ---------------------------------------------------------------------------
extern "C" void kernel_launch(void* const* d_in, const int* in_sizes, int n_in,
                              void* d_out, int out_size, void* d_ws, size_t ws_size,
                              hipStream_t stream) {
    const int*   data = (const int*)d_in[0];
    const float* emb  = (const float*)d_in[1];
    const float* fw1  = (const float*)d_in[2];
    const float* fb1  = (const float*)d_in[3];
    const float* fw2  = (const float*)d_in[4];
    const float* fb2  = (const float*)d_in[5];
    const float* Wf   = (const float*)d_in[6];
    const float* bf   = (const float*)d_in[7];
    float* out = (float*)d_out;

    float* X  = (float*)d_ws;                       // 1048576 floats
    float* VA = X + NB * NVEC * NDIM;               // 1048576
    float* VB = VA + NB * NVEC * NDIM;              // 1048576
    float* U0 = VB + NB * NVEC * NDIM;              // 66048
    float* U1 = U0 + NB * USIZE;                    // 66048

    k_embed<<<dim3(NB * NVEC * NDIM / 4 / 256), 256, 0, stream>>>(data, emb, bf, X, out, U0);

    const float* Vcur = X;
    float* Vnext = VA;
    for (int t = 0; t < NW; ++t) {
        int i = NW - 1 - t;
        float* Ucur  = (t & 1) ? U1 : U0;
        float* Unext = (t & 1) ? U0 : U1;
        k_U<<<dim3(MS, NB), 1024, 0, stream>>>(Vcur, fw2 + (size_t)i * NHID * NVEC,
                                               fb2 + (size_t)i * NVEC, Ucur);
        if (i > 0) {
            k_applyF<false><<<dim3(NVEC / 64, NB), 256, 0, stream>>>(
                X, fw1 + (size_t)i * NDIM * NHID, fb1 + (size_t)i * NHID,
                Ucur, Unext, Vnext, nullptr, nullptr);
            Vcur = Vnext;
            Vnext = (Vnext == VA) ? VB : VA;
        } else {
            k_applyF<true><<<dim3(NVEC / 64, NB), 256, 0, stream>>>(
                X, fw1, fb1, Ucur, nullptr, nullptr, Wf, out);
        }
    }
}

// Round 2
// 219.561 us; speedup vs baseline: 1.8085x; 1.8085x over previous
//
#include <hip/hip_runtime.h>

#define NB 16
#define NVEC 2048
#define NDIM 32
#define NW 4
#define NHID 128
#define NCLASS 10
#define MS 16              // m-splits for k_U (each block reduces 128 m's)
#define USIZE (129 * 32)   // 4128 floats per b: rows 0..127 = fw2@V, row 128 = fb2^T@V

// tanh-approx GELU; validated absmax vs ref in prior session.
__device__ __forceinline__ float gelu_fast(float x) {
    float t = 1.5957691216057308f * x * (1.0f + 0.044715f * x * x);
    return x / (1.0f + __expf(-t));
}

// ---------------------------------------------------------------------------
// Embed gather (float4) + out=bias init. grid 1024 x 256.
__global__ __launch_bounds__(256) void k_embed(const int* __restrict__ data,
                                               const float* __restrict__ emb,
                                               const float* __restrict__ bf,
                                               float* __restrict__ X,
                                               float* __restrict__ out) {
    int gid = blockIdx.x * 256 + threadIdx.x;      // NB*NVEC*NDIM/4 = 262144
    int row = gid >> 3, sub = gid & 7;             // 8 float4 per 32-float row
    ((float4*)X)[gid] = ((const float4*)emb)[data[row] * 8 + sub];
    if (blockIdx.x == 0 && threadIdx.x < NB * NCLASS)
        out[threadIdx.x] = bf[threadIdx.x % NCLASS];
}

// ---------------------------------------------------------------------------
// Partial U: grid (MS, NB), 1024 threads (16 waves -> 4/SIMD).
// Each thread: 1 k-row x 4 d over 128 m. fw2 row streamed from global
// (L1-resident, one 64B line per lane per 16-m tile); Vs reads are full-wave
// broadcasts (d0 wave-uniform). Plain float4 partial stores -- NO atomics
// (R1 post-mortem: 16-way same-address f32 atomics = 66us drain).
__global__ __launch_bounds__(1024) void k_U(const float* __restrict__ V,
                                            const float* __restrict__ fw2,
                                            const float* __restrict__ fb2,
                                            float* __restrict__ Upart) {
    __shared__ float Vs[128 * 32];       // [mm][d], 16 KB
    __shared__ float cred[4][33];
    int ms = blockIdx.x, b = blockIdx.y;
    int tid = threadIdx.x;
    int m0 = ms * 128;
    ((float4*)Vs)[tid] = ((const float4*)(V + (b * NVEC + m0) * NDIM))[tid];
    int k1 = tid & 127, d0 = (tid >> 7) * 4;   // d0 uniform per wave
    const float* wrow = fw2 + k1 * NVEC + m0;
    float acc[4] = {0.f, 0.f, 0.f, 0.f};
    __syncthreads();
#pragma unroll
    for (int mt = 0; mt < 128; mt += 16) {
        float4 w4[4];
#pragma unroll
        for (int j = 0; j < 4; ++j) w4[j] = ((const float4*)(wrow + mt))[j];
        const float* wf = (const float*)w4;
#pragma unroll
        for (int j = 0; j < 16; ++j) {
            float w = wf[j];
            float4 v = *(const float4*)&Vs[(mt + j) * 32 + d0];  // broadcast
            acc[0] += w * v.x; acc[1] += w * v.y;
            acc[2] += w * v.z; acc[3] += w * v.w;
        }
    }
    float* Up = Upart + ((size_t)ms * NB + b) * USIZE;
    *(float4*)&Up[k1 * 32 + d0] = make_float4(acc[0], acc[1], acc[2], acc[3]);
    // bias row partial: sum_m fb2[m0+m] * Vs[m][d]
    if (tid < 128) {
        int d = tid & 31, seg = tid >> 5;
        float ca = 0.f;
#pragma unroll 8
        for (int mm = seg * 32; mm < seg * 32 + 32; ++mm)
            ca += fb2[m0 + mm] * Vs[mm * 32 + d];
        cred[seg][d] = ca;
    }
    __syncthreads();
    if (tid < 32)
        Up[128 * 32 + tid] = cred[0][tid] + cred[1][tid] + cred[2][tid] + cred[3][tid];
}

// ---------------------------------------------------------------------------
// Reduce the MS partials into final U. grid (NB, 8), 256 threads.
// Per active thread: 16 independent float4 loads + 1 store. ~1-2 us.
__global__ __launch_bounds__(256) void k_Ured(const float* __restrict__ Upart,
                                              float* __restrict__ U) {
    int b = blockIdx.x;
    int i4 = blockIdx.y * 129 + threadIdx.x;       // USIZE/4 = 1032 = 8*129
    if (threadIdx.x >= 129) return;
    float4 s = ((const float4*)Upart)[(size_t)b * (USIZE / 4) + i4];
#pragma unroll
    for (int ms = 1; ms < MS; ++ms) {
        float4 v = ((const float4*)Upart)[((size_t)ms * NB + b) * (USIZE / 4) + i4];
        s.x += v.x; s.y += v.y; s.z += v.z; s.w += v.w;
    }
    ((float4*)U)[b * (USIZE / 4) + i4] = s;
}

// ---------------------------------------------------------------------------
// Fused h+apply, single 64-row pass. grid (NVEC/64, NB), 256 threads.
// Loads FINAL U (16.5 KB). LAST: classifier folded in-register.
template <bool LAST>
__global__ __launch_bounds__(256) void k_applyF(const float* __restrict__ X,
                                                const float* __restrict__ fw1l,
                                                const float* __restrict__ fb1l,
                                                const float* __restrict__ U,
                                                float* __restrict__ Vout,
                                                const float* __restrict__ Wf,
                                                float* __restrict__ out) {
    __shared__ float Us[USIZE];          // 4128
    __shared__ float w1s[NDIM * NHID];   // 4096, [d][k]
    __shared__ float xs[64][33];         // padded: conflict-free row reads
    __shared__ float hs[64 * 132];       // [r][k]
    __shared__ float ored[4][NCLASS];
    int ng = blockIdx.x, b = blockIdx.y;
    int tid = threadIdx.x;
    int n0 = ng * 64;

    for (int i4 = tid; i4 < USIZE / 4; i4 += 256)
        ((float4*)Us)[i4] = ((const float4*)(U + (size_t)b * USIZE))[i4];
#pragma unroll
    for (int j = 0; j < 4; ++j)
        ((float4*)w1s)[tid + j * 256] = ((const float4*)fw1l)[tid + j * 256];
#pragma unroll
    for (int j = 0; j < 2; ++j) {
        int i4 = tid + j * 256;
        float4 v = ((const float4*)(X + (b * NVEC + n0) * NDIM))[i4];
        int r = i4 >> 3, c4 = (i4 & 7) * 4;
        xs[r][c4] = v.x; xs[r][c4 + 1] = v.y;
        xs[r][c4 + 2] = v.z; xs[r][c4 + 3] = v.w;
    }
    __syncthreads();

    {   // h = gelu(X@fw1 + fb1): 4 rows x 8 k per thread
        int kg = tid & 15, rg = tid >> 4;
        int k0 = kg * 8, r0 = rg * 4;
        float acc[4][8];
#pragma unroll
        for (int j = 0; j < 8; ++j) {
            float bv = fb1l[k0 + j];
            acc[0][j] = bv; acc[1][j] = bv; acc[2][j] = bv; acc[3][j] = bv;
        }
#pragma unroll 8
        for (int d = 0; d < NDIM; ++d) {
            float4 wa = *(const float4*)&w1s[d * NHID + k0];
            float4 wb = *(const float4*)&w1s[d * NHID + k0 + 4];
            float wk[8] = {wa.x, wa.y, wa.z, wa.w, wb.x, wb.y, wb.z, wb.w};
            float x0 = xs[r0][d], x1 = xs[r0 + 1][d];
            float x2 = xs[r0 + 2][d], x3 = xs[r0 + 3][d];
#pragma unroll
            for (int j = 0; j < 8; ++j) {
                acc[0][j] += x0 * wk[j];
                acc[1][j] += x1 * wk[j];
                acc[2][j] += x2 * wk[j];
                acc[3][j] += x3 * wk[j];
            }
        }
#pragma unroll
        for (int r = 0; r < 4; ++r) {
            float4 o0, o1;
            o0.x = gelu_fast(acc[r][0]); o0.y = gelu_fast(acc[r][1]);
            o0.z = gelu_fast(acc[r][2]); o0.w = gelu_fast(acc[r][3]);
            o1.x = gelu_fast(acc[r][4]); o1.y = gelu_fast(acc[r][5]);
            o1.z = gelu_fast(acc[r][6]); o1.w = gelu_fast(acc[r][7]);
            *(float4*)&hs[(r0 + r) * 132 + k0] = o0;
            *(float4*)&hs[(r0 + r) * 132 + k0 + 4] = o1;
        }
    }
    __syncthreads();

    {   // apply: V_new = h @ U + U[128,:]; 2 rows x 4 d per thread
        int dg = tid & 7, rga = tid >> 3;
        int d0 = dg * 4, r0 = rga * 2;
        float4 a0 = *(const float4*)&Us[NHID * 32 + d0];
        float4 a1 = a0;
#pragma unroll 8
        for (int k = 0; k < NHID; k += 4) {
            float4 h0 = *(const float4*)&hs[r0 * 132 + k];
            float4 h1 = *(const float4*)&hs[(r0 + 1) * 132 + k];
            float4 u0 = *(const float4*)&Us[(k + 0) * 32 + d0];
            float4 u1 = *(const float4*)&Us[(k + 1) * 32 + d0];
            float4 u2 = *(const float4*)&Us[(k + 2) * 32 + d0];
            float4 u3 = *(const float4*)&Us[(k + 3) * 32 + d0];
            a0.x += h0.x * u0.x + h0.y * u1.x + h0.z * u2.x + h0.w * u3.x;
            a0.y += h0.x * u0.y + h0.y * u1.y + h0.z * u2.y + h0.w * u3.y;
            a0.z += h0.x * u0.z + h0.y * u1.z + h0.z * u2.z + h0.w * u3.z;
            a0.w += h0.x * u0.w + h0.y * u1.w + h0.z * u2.w + h0.w * u3.w;
            a1.x += h1.x * u0.x + h1.y * u1.x + h1.z * u2.x + h1.w * u3.x;
            a1.y += h1.x * u0.y + h1.y * u1.y + h1.z * u2.y + h1.w * u3.y;
            a1.z += h1.x * u0.z + h1.y * u1.z + h1.z * u2.z + h1.w * u3.z;
            a1.w += h1.x * u0.w + h1.y * u1.w + h1.z * u2.w + h1.w * u3.w;
        }
        if constexpr (!LAST) {
            *(float4*)&Vout[(b * NVEC + n0 + r0) * NDIM + d0] = a0;
            *(float4*)&Vout[(b * NVEC + n0 + r0 + 1) * NDIM + d0] = a1;
        } else {
            // classifier fused: out[b,c] += sum V[n,d] * Wf[n*32+d, c]
            float accC[NCLASS];
#pragma unroll
            for (int c = 0; c < NCLASS; ++c) accC[c] = 0.f;
            float va[2][4] = {{a0.x, a0.y, a0.z, a0.w}, {a1.x, a1.y, a1.z, a1.w}};
#pragma unroll
            for (int r = 0; r < 2; ++r)
#pragma unroll
                for (int dd = 0; dd < 4; ++dd) {
                    int jj = (n0 + r0 + r) * NDIM + d0 + dd;
                    const float2* wr = (const float2*)(Wf + (size_t)jj * NCLASS);
                    float v = va[r][dd];
#pragma unroll
                    for (int p = 0; p < 5; ++p) {
                        float2 w = wr[p];
                        accC[2 * p]     += v * w.x;
                        accC[2 * p + 1] += v * w.y;
                    }
                }
            int lane = tid & 63, wv = tid >> 6;
#pragma unroll
            for (int c = 0; c < NCLASS; ++c)
#pragma unroll
                for (int off = 32; off >= 1; off >>= 1)
                    accC[c] += __shfl_down(accC[c], off, 64);
            if (lane == 0) {
#pragma unroll
                for (int c = 0; c < NCLASS; ++c) ored[wv][c] = accC[c];
            }
            __syncthreads();
            if (tid < NCLASS)
                atomicAdd(&out[b * NCLASS + tid],
                          ored[0][tid] + ored[1][tid] + ored[2][tid] + ored[3][tid]);
        }
    }
}

// ---------------------------------------------------------------------------
extern "C" void kernel_launch(void* const* d_in, const int* in_sizes, int n_in,
                              void* d_out, int out_size, void* d_ws, size_t ws_size,
                              hipStream_t stream) {
    const int*   data = (const int*)d_in[0];
    const float* emb  = (const float*)d_in[1];
    const float* fw1  = (const float*)d_in[2];
    const float* fb1  = (const float*)d_in[3];
    const float* fw2  = (const float*)d_in[4];
    const float* fb2  = (const float*)d_in[5];
    const float* Wf   = (const float*)d_in[6];
    const float* bf   = (const float*)d_in[7];
    float* out = (float*)d_out;

    float* X     = (float*)d_ws;                    // 1048576 floats
    float* VA    = X + NB * NVEC * NDIM;            // 1048576
    float* VB    = VA + NB * NVEC * NDIM;           // 1048576
    float* Upart = VB + NB * NVEC * NDIM;           // MS*NB*USIZE = 1056768
    float* U     = Upart + (size_t)MS * NB * USIZE; // 66048

    k_embed<<<dim3(NB * NVEC * NDIM / 4 / 256), 256, 0, stream>>>(data, emb, bf, X, out);

    const float* Vcur = X;
    float* Vnext = VA;
    for (int t = 0; t < NW; ++t) {
        int i = NW - 1 - t;
        k_U<<<dim3(MS, NB), 1024, 0, stream>>>(Vcur, fw2 + (size_t)i * NHID * NVEC,
                                               fb2 + (size_t)i * NVEC, Upart);
        k_Ured<<<dim3(NB, 8), 256, 0, stream>>>(Upart, U);
        if (i > 0) {
            k_applyF<false><<<dim3(NVEC / 64, NB), 256, 0, stream>>>(
                X, fw1 + (size_t)i * NDIM * NHID, fb1 + (size_t)i * NHID,
                U, Vnext, nullptr, nullptr);
            Vcur = Vnext;
            Vnext = (Vnext == VA) ? VB : VA;
        } else {
            k_applyF<true><<<dim3(NVEC / 64, NB), 256, 0, stream>>>(
                X, fw1, fb1, U, nullptr, Wf, out);
        }
    }
}